// Round 3
// baseline (230.874 us; speedup 1.0000x reference)
//
#include <hip/hip_runtime.h>

// B=2, L=2048, D=1024, H=16, DK=DV=64, M=4096.
// R3: k_gemm -> m97 global_load_lds staging (unpadded LDS, 2-barrier K-loop);
//     k_attn -> double-buffered LDS + QK/PV cross-iteration software pipeline,
//               K/V staged via global_load_lds (K rows source-permuted per lane).

typedef __bf16 bf16;
typedef __bf16 bf16x2 __attribute__((ext_vector_type(2)));
typedef __bf16 bf16x4 __attribute__((ext_vector_type(4)));
typedef __bf16 bf16x8 __attribute__((ext_vector_type(8)));
typedef float floatx4 __attribute__((ext_vector_type(4)));
typedef int intx4 __attribute__((ext_vector_type(4)));

#define MFMA16(a, b, c) __builtin_amdgcn_mfma_f32_16x16x32_bf16((a), (b), (c), 0, 0, 0)

__device__ __forceinline__ void gll16(const bf16* g, bf16* l) {
  __builtin_amdgcn_global_load_lds((const __attribute__((address_space(1))) void*)g,
                                   (__attribute__((address_space(3))) void*)l, 16, 0, 0);
}

// ---------------- prep: x (fp32) -> xb (bf16) ----------------
__global__ __launch_bounds__(256) void k_prep_x(const float* __restrict__ x, bf16* __restrict__ xb) {
  const int i = (blockIdx.x * 256 + threadIdx.x) * 4;
  const float4 v = *reinterpret_cast<const float4*>(x + i);
  bf16x4 o = {(bf16)v.x, (bf16)v.y, (bf16)v.z, (bf16)v.w};
  *reinterpret_cast<bf16x4*>(xb + i) = o;
}

// ---------------- prep: W [1024][1024] fp32 -> WT [n][k] bf16 ----------------
__global__ __launch_bounds__(256) void k_prep_w(const float* __restrict__ Wq, const float* __restrict__ Wk,
                                                const float* __restrict__ Wv, const float* __restrict__ Wo,
                                                bf16* __restrict__ WT) {
  __shared__ float tile[32][33];
  const int z = blockIdx.z;
  const float* W = (z == 0) ? Wq : (z == 1) ? Wk : (z == 2) ? Wv : Wo;
  const int n0 = blockIdx.x * 32, k0 = blockIdx.y * 32;
  const int tx = threadIdx.x, ty = threadIdx.y;
#pragma unroll
  for (int j = 0; j < 32; j += 8)
    tile[ty + j][tx] = W[(size_t)(k0 + ty + j) * 1024 + n0 + tx];
  __syncthreads();
#pragma unroll
  for (int j = 0; j < 32; j += 8)
    WT[(size_t)(z * 1024 + n0 + ty + j) * 1024 + k0 + tx] = (bf16)tile[tx][ty + j];
}

// ---------------- GEMM (m97 structure): C = A[M][1024] * Bt[N][1024]^T ----------------
template <int MODE>
__global__ __launch_bounds__(256) void k_gemm(const bf16* __restrict__ A, const bf16* __restrict__ Bt,
                                              const float* __restrict__ X, float* __restrict__ Y,
                                              bf16* __restrict__ QB, bf16* __restrict__ KB,
                                              bf16* __restrict__ VTB) {
  __shared__ __align__(16) bf16 As[128 * 64];  // unpadded: global_load_lds needs lane-contiguous dest
  __shared__ __align__(16) bf16 Bs[128 * 64];
  const int t = threadIdx.x;
  const int lane = t & 63, wv = t >> 6;
  const int qd = lane >> 4, col = lane & 15;
  const int wm = wv >> 1, wn = wv & 1;
  const int m0 = blockIdx.x * 128, n0 = blockIdx.y * 128;
  // staging: round rd covers LDS rows rd*32 + wv*8 + lane/8, cols (lane&7)*8
  const int srow = wv * 8 + (lane >> 3);
  const int scol = (lane & 7) * 8;
  const bf16* Ag = A + (size_t)(m0 + srow) * 1024 + scol;
  const bf16* Bg = Bt + (size_t)(n0 + srow) * 1024 + scol;

  floatx4 acc[4][4] = {};

  for (int kt = 0; kt < 1024; kt += 64) {
    __syncthreads();  // previous tile reads done
#pragma unroll
    for (int rd = 0; rd < 4; rd++) {
      gll16(Ag + (size_t)rd * 32 * 1024 + kt, As + (rd * 32 + wv * 8) * 64);
      gll16(Bg + (size_t)rd * 32 * 1024 + kt, Bs + (rd * 32 + wv * 8) * 64);
    }
    __syncthreads();  // drains vmcnt -> tile staged
#pragma unroll
    for (int ks = 0; ks < 2; ks++) {
      bf16x8 af[4], bfr[4];
#pragma unroll
      for (int i = 0; i < 4; i++)
        af[i] = *reinterpret_cast<const bf16x8*>(As + (wm * 64 + i * 16 + col) * 64 + ks * 32 + qd * 8);
#pragma unroll
      for (int i = 0; i < 4; i++)
        bfr[i] = *reinterpret_cast<const bf16x8*>(Bs + (wn * 64 + i * 16 + col) * 64 + ks * 32 + qd * 8);
#pragma unroll
      for (int i = 0; i < 4; i++)
#pragma unroll
        for (int j = 0; j < 4; j++)
          acc[i][j] = MFMA16(af[i], bfr[j], acc[i][j]);
    }
  }

#pragma unroll
  for (int i = 0; i < 4; i++) {
#pragma unroll
    for (int j = 0; j < 4; j++) {
      const int mb = m0 + wm * 64 + i * 16 + qd * 4;
      const int n = n0 + wn * 64 + j * 16 + col;
      if (MODE == 0) {
        const int seg = n >> 10;
        const int h = (n & 1023) >> 6, dd = n & 63;
#pragma unroll
        for (int r = 0; r < 4; r++) {
          const int m = mb + r;
          const int bb = m >> 11, l = m & 2047;
          const float v = acc[i][j][r];
          if (seg == 0)
            QB[((size_t)(bb * 16 + h) * 2048 + l) * 64 + dd] = (bf16)(v * 0.125f);
          else if (seg == 1)
            KB[((size_t)(bb * 16 + h) * 2048 + l) * 64 + dd] = (bf16)v;
          else
            VTB[((size_t)(bb * 16 + h) * 64 + dd) * 2048 + l] = (bf16)v;
        }
      } else {
#pragma unroll
        for (int r = 0; r < 4; r++) {
          const int m = mb + r;
          Y[(size_t)m * 1024 + n] = acc[i][j][r] + X[(size_t)m * 1024 + n];
        }
      }
    }
  }
}

// ---------------- flash attention: S^T trick + dbuf + QK/PV pipeline ----------------
// grid (16 qblocks of 128 rows, 32 b*h), 4 waves; wave owns 32 q-rows (2 tiles).
// Body i: [A barrier] stage(i)->buf[i&1] via global_load_lds; exp(i-1); PV(i-1)
//         [B barrier: vmcnt drained] QK(i).  One tile of slack hides the DMA.
__global__ __launch_bounds__(256) void k_attn(const bf16* __restrict__ QB, const bf16* __restrict__ KB,
                                              const bf16* __restrict__ VTB, bf16* __restrict__ OB) {
  __shared__ __align__(16) bf16 Ks[2][64 * 64];  // [buf][perm(kpos)][dk]
  __shared__ __align__(16) bf16 Vs[2][64 * 64];  // [buf][dv][kpos]
  const int t = threadIdx.x;
  const int lane = t & 63, wv = t >> 6;
  const int qd = lane >> 4, col = lane & 15;
  const int bh = blockIdx.y;
  const int qr = blockIdx.x * 128 + wv * 32;
  // staging lane geometry: round rd covers LDS rows rd*32 + wv*8 + lane/8
  const int lrow0 = wv * 8 + (lane >> 3);
  const int scol = (lane & 7) * 8;
  // K inverse permutation: LDS row -> kpos (perm: kpos[b4b3|b2|b1b0] -> lds[b2|b4b3|b1b0])
  const int kg0 = ((lrow0 >> 5) << 5) + (((lrow0 >> 2) & 3) << 3) + (((lrow0 >> 4) & 1) << 2) + (lrow0 & 3);
  const int r1 = lrow0 + 32;
  const int kg1 = ((r1 >> 5) << 5) + (((r1 >> 2) & 3) << 3) + (((r1 >> 4) & 1) << 2) + (r1 & 3);
  const bf16* Kg0 = KB + ((size_t)bh * 2048 + kg0) * 64 + scol;
  const bf16* Kg1 = KB + ((size_t)bh * 2048 + kg1) * 64 + scol;
  const bf16* Vg0 = VTB + ((size_t)bh * 64 + lrow0) * 2048 + scol;
  const bf16* Vg1 = VTB + ((size_t)bh * 64 + lrow0 + 32) * 2048 + scol;

  // persistent Q fragments (MFMA B-operand = Q^T)
  bf16x8 bQ[2][2];
#pragma unroll
  for (int qt = 0; qt < 2; qt++)
#pragma unroll
    for (int s = 0; s < 2; s++)
      bQ[qt][s] = *reinterpret_cast<const bf16x8*>(QB + ((size_t)bh * 2048 + qr + qt * 16 + col) * 64 + s * 32 + qd * 8);

  floatx4 oacc[2][4] = {};
  float lsum[2] = {0.f, 0.f};
  floatx4 scur[2][4];  // S^T of current tile
  int pk[2][4][2];     // packed bf16 P of previous tile

#define STAGE(i)                                                      \
  do {                                                                \
    const int b_ = (i) & 1;                                           \
    gll16(Kg0 + (size_t)(i) * 4096, &Ks[b_][(wv * 8) * 64]);          \
    gll16(Kg1 + (size_t)(i) * 4096, &Ks[b_][(32 + wv * 8) * 64]);     \
    gll16(Vg0 + (i) * 64, &Vs[b_][(wv * 8) * 64]);                    \
    gll16(Vg1 + (i) * 64, &Vs[b_][(32 + wv * 8) * 64]);               \
  } while (0)

#define QK(i)                                                                                   \
  do {                                                                                          \
    const bf16* ks_ = Ks[(i) & 1];                                                              \
    _Pragma("unroll") for (int nt = 0; nt < 4; nt++) {                                          \
      bf16x8 a0 = *reinterpret_cast<const bf16x8*>(ks_ + (nt * 16 + col) * 64 + qd * 8);        \
      bf16x8 a1 = *reinterpret_cast<const bf16x8*>(ks_ + (nt * 16 + col) * 64 + 32 + qd * 8);   \
      _Pragma("unroll") for (int qt = 0; qt < 2; qt++) {                                        \
        floatx4 z = {0.f, 0.f, 0.f, 0.f};                                                       \
        z = MFMA16(a0, bQ[qt][0], z);                                                           \
        z = MFMA16(a1, bQ[qt][1], z);                                                           \
        scur[qt][nt] = z;                                                                       \
      }                                                                                         \
    }                                                                                           \
  } while (0)

#define EXPPACK()                                                                               \
  do {                                                                                          \
    _Pragma("unroll") for (int qt = 0; qt < 2; qt++) {                                          \
      _Pragma("unroll") for (int nt = 0; nt < 4; nt++) {                                        \
        const float e0 = __expf(scur[qt][nt][0]), e1 = __expf(scur[qt][nt][1]);                 \
        const float e2 = __expf(scur[qt][nt][2]), e3 = __expf(scur[qt][nt][3]);                 \
        lsum[qt] += (e0 + e1) + (e2 + e3);                                                      \
        bf16x2 p01, p23;                                                                        \
        p01[0] = (bf16)e0; p01[1] = (bf16)e1;                                                   \
        p23[0] = (bf16)e2; p23[1] = (bf16)e3;                                                   \
        pk[qt][nt][0] = __builtin_bit_cast(int, p01);                                           \
        pk[qt][nt][1] = __builtin_bit_cast(int, p23);                                           \
      }                                                                                         \
    }                                                                                           \
  } while (0)

#define PV(i)                                                                                   \
  do {                                                                                          \
    const bf16* vs_ = Vs[(i) & 1];                                                              \
    bf16x8 bV[4][2];                                                                            \
    _Pragma("unroll") for (int nd = 0; nd < 4; nd++) {                                          \
      bV[nd][0] = *reinterpret_cast<const bf16x8*>(vs_ + (nd * 16 + col) * 64 + qd * 8);        \
      bV[nd][1] = *reinterpret_cast<const bf16x8*>(vs_ + (nd * 16 + col) * 64 + 32 + qd * 8);   \
    }                                                                                           \
    _Pragma("unroll") for (int qt = 0; qt < 2; qt++) {                                          \
      _Pragma("unroll") for (int s = 0; s < 2; s++) {                                           \
        intx4 w;                                                                                \
        w[0] = pk[qt][2 * s][0]; w[1] = pk[qt][2 * s][1];                                       \
        w[2] = pk[qt][2 * s + 1][0]; w[3] = pk[qt][2 * s + 1][1];                               \
        const bf16x8 aP = __builtin_bit_cast(bf16x8, w);                                        \
        _Pragma("unroll") for (int nd = 0; nd < 4; nd++)                                        \
          oacc[qt][nd] = MFMA16(aP, bV[nd][s], oacc[qt][nd]);                                   \
      }                                                                                         \
    }                                                                                           \
  } while (0)

  STAGE(0);
  __syncthreads();  // tile 0 staged
  QK(0);
  for (int i = 1; i < 32; i++) {
    __syncthreads();  // A: tile i-2 reads complete on all waves
    STAGE(i);
    EXPPACK();  // exp(i-1)
    PV(i - 1);
    __syncthreads();  // B: vmcnt drained -> tile i staged
    QK(i);
  }
  EXPPACK();  // exp(31)
  PV(31);

  // final l reduction across quad groups; normalize + store
#pragma unroll
  for (int qt = 0; qt < 2; qt++) {
    lsum[qt] += __shfl_xor(lsum[qt], 16);
    lsum[qt] += __shfl_xor(lsum[qt], 32);
  }
  const int bb = bh >> 4, h = bh & 15;
#pragma unroll
  for (int qt = 0; qt < 2; qt++) {
#pragma unroll
    for (int r = 0; r < 4; r++) {
      const float linv = 1.f / __shfl(lsum[qt], qd * 4 + r);
      const size_t m = (size_t)bb * 2048 + qr + qt * 16 + qd * 4 + r;
#pragma unroll
      for (int nd = 0; nd < 4; nd++)
        OB[m * 1024 + h * 64 + nd * 16 + col] = (bf16)(oacc[qt][nd][r] * linv);
    }
  }
#undef STAGE
#undef QK
#undef EXPPACK
#undef PV
}

// ---------------- LayerNorm ----------------
__global__ __launch_bounds__(256) void k_ln(const float* __restrict__ Yin, const float* __restrict__ gamma,
                                            const float* __restrict__ beta, float* __restrict__ out) {
  __shared__ float red[8];
  const int row = blockIdx.x, t = threadIdx.x;
  const float4 v = *reinterpret_cast<const float4*>(Yin + (size_t)row * 1024 + t * 4);
  float s = v.x + v.y + v.z + v.w;
  float ss = v.x * v.x + v.y * v.y + v.z * v.z + v.w * v.w;
#pragma unroll
  for (int d = 1; d < 64; d <<= 1) {
    s += __shfl_xor(s, d);
    ss += __shfl_xor(ss, d);
  }
  if ((t & 63) == 0) {
    red[t >> 6] = s;
    red[4 + (t >> 6)] = ss;
  }
  __syncthreads();
  s = red[0] + red[1] + red[2] + red[3];
  ss = red[4] + red[5] + red[6] + red[7];
  const float mu = s * (1.f / 1024.f);
  const float var = ss * (1.f / 1024.f) - mu * mu;
  const float rs = rsqrtf(var + 1e-6f);
  const float4 g = *reinterpret_cast<const float4*>(gamma + t * 4);
  const float4 bt = *reinterpret_cast<const float4*>(beta + t * 4);
  float4 o;
  o.x = (v.x - mu) * rs * g.x + bt.x;
  o.y = (v.y - mu) * rs * g.y + bt.y;
  o.z = (v.z - mu) * rs * g.z + bt.z;
  o.w = (v.w - mu) * rs * g.w + bt.w;
  *reinterpret_cast<float4*>(out + (size_t)row * 1024 + t * 4) = o;
}

extern "C" void kernel_launch(void* const* d_in, const int* in_sizes, int n_in,
                              void* d_out, int out_size, void* d_ws, size_t ws_size,
                              hipStream_t stream) {
  (void)in_sizes; (void)n_in; (void)out_size; (void)ws_size;
  const float* x = (const float*)d_in[0];
  const float* Wq = (const float*)d_in[1];
  const float* Wk = (const float*)d_in[2];
  const float* Wv = (const float*)d_in[3];
  const float* Wo = (const float*)d_in[4];
  const float* gamma = (const float*)d_in[5];
  const float* beta = (const float*)d_in[6];

  char* ws = (char*)d_ws;
  const size_t MB = 1ull << 20;
  bf16* XB = (bf16*)(ws);
  bf16* OB = (bf16*)(ws);
  bf16* WT = (bf16*)(ws + 8 * MB);
  bf16* QB = (bf16*)(ws + 16 * MB);
  bf16* KB = (bf16*)(ws + 24 * MB);
  bf16* VTB = (bf16*)(ws + 32 * MB);
  float* Y = (float*)(ws + 16 * MB);

  k_prep_x<<<4096, 256, 0, stream>>>(x, XB);
  k_prep_w<<<dim3(32, 32, 4), dim3(32, 8), 0, stream>>>(Wq, Wk, Wv, Wo, WT);
  k_gemm<0><<<dim3(32, 24), 256, 0, stream>>>(XB, WT, nullptr, nullptr, QB, KB, VTB);
  k_attn<<<dim3(16, 32), 256, 0, stream>>>(QB, KB, VTB, OB);
  k_gemm<1><<<dim3(32, 8), 256, 0, stream>>>(OB, WT + (size_t)3072 * 1024, x, Y,
                                             nullptr, nullptr, nullptr);
  k_ln<<<4096, 256, 0, stream>>>(Y, gamma, beta, (float*)d_out);
}

// Round 4
// 209.320 us; speedup vs baseline: 1.1030x; 1.1030x over previous
//
#include <hip/hip_runtime.h>

// B=2, L=2048, D=1024, H=16, DK=DV=64, M=4096.
// R4: XOR-swizzled gll16 staging (chunk c of row r at slot c^(r&7)) in both
//     k_gemm and k_attn -> conflict-free b128 fragment reads with unpadded rows.
//     Attn keeps the R3 QK/PV cross-iteration pipeline.

typedef __bf16 bf16;
typedef __bf16 bf16x2 __attribute__((ext_vector_type(2)));
typedef __bf16 bf16x4 __attribute__((ext_vector_type(4)));
typedef __bf16 bf16x8 __attribute__((ext_vector_type(8)));
typedef float floatx4 __attribute__((ext_vector_type(4)));
typedef int intx4 __attribute__((ext_vector_type(4)));

#define MFMA16(a, b, c) __builtin_amdgcn_mfma_f32_16x16x32_bf16((a), (b), (c), 0, 0, 0)

__device__ __forceinline__ void gll16(const bf16* g, bf16* l) {
  __builtin_amdgcn_global_load_lds((const __attribute__((address_space(1))) void*)g,
                                   (__attribute__((address_space(3))) void*)l, 16, 0, 0);
}

// ---------------- prep: x (fp32) -> xb (bf16) ----------------
__global__ __launch_bounds__(256) void k_prep_x(const float* __restrict__ x, bf16* __restrict__ xb) {
  const int i = (blockIdx.x * 256 + threadIdx.x) * 4;
  const float4 v = *reinterpret_cast<const float4*>(x + i);
  bf16x4 o = {(bf16)v.x, (bf16)v.y, (bf16)v.z, (bf16)v.w};
  *reinterpret_cast<bf16x4*>(xb + i) = o;
}

// ---------------- prep: W [1024][1024] fp32 -> WT [n][k] bf16 ----------------
__global__ __launch_bounds__(256) void k_prep_w(const float* __restrict__ Wq, const float* __restrict__ Wk,
                                                const float* __restrict__ Wv, const float* __restrict__ Wo,
                                                bf16* __restrict__ WT) {
  __shared__ float tile[32][33];
  const int z = blockIdx.z;
  const float* W = (z == 0) ? Wq : (z == 1) ? Wk : (z == 2) ? Wv : Wo;
  const int n0 = blockIdx.x * 32, k0 = blockIdx.y * 32;
  const int tx = threadIdx.x, ty = threadIdx.y;
#pragma unroll
  for (int j = 0; j < 32; j += 8)
    tile[ty + j][tx] = W[(size_t)(k0 + ty + j) * 1024 + n0 + tx];
  __syncthreads();
#pragma unroll
  for (int j = 0; j < 32; j += 8)
    WT[(size_t)(z * 1024 + n0 + ty + j) * 1024 + k0 + tx] = (bf16)tile[tx][ty + j];
}

// ---------------- GEMM: C = A[M][1024] * Bt[N][1024]^T, swizzled staging ----------------
template <int MODE>
__global__ __launch_bounds__(256) void k_gemm(const bf16* __restrict__ A, const bf16* __restrict__ Bt,
                                              const float* __restrict__ X, float* __restrict__ Y,
                                              bf16* __restrict__ QB, bf16* __restrict__ KB,
                                              bf16* __restrict__ VTB) {
  __shared__ __align__(16) bf16 As[128 * 64];  // slot c^(r&7) holds chunk c of row r
  __shared__ __align__(16) bf16 Bs[128 * 64];
  const int t = threadIdx.x;
  const int lane = t & 63, wv = t >> 6;
  const int qd = lane >> 4, col = lane & 15;
  const int c7 = col & 7;
  const int wm = wv >> 1, wn = wv & 1;
  const int m0 = blockIdx.x * 128, n0 = blockIdx.y * 128;
  // staging: lane covers LDS (row base + lane/8, slot lane&7) -> source chunk (lane&7)^(lane>>3)
  const int srow = wv * 8 + (lane >> 3);
  const int scol = ((lane & 7) ^ (lane >> 3)) * 8;
  const bf16* Ag = A + (size_t)(m0 + srow) * 1024 + scol;
  const bf16* Bg = Bt + (size_t)(n0 + srow) * 1024 + scol;

  floatx4 acc[4][4] = {};

  for (int kt = 0; kt < 1024; kt += 64) {
    __syncthreads();
#pragma unroll
    for (int rd = 0; rd < 4; rd++) {
      gll16(Ag + (size_t)rd * 32 * 1024 + kt, As + (rd * 32 + wv * 8) * 64);
      gll16(Bg + (size_t)rd * 32 * 1024 + kt, Bs + (rd * 32 + wv * 8) * 64);
    }
    __syncthreads();
#pragma unroll
    for (int ks = 0; ks < 2; ks++) {
      bf16x8 af[4], bfr[4];
#pragma unroll
      for (int i = 0; i < 4; i++)
        af[i] = *reinterpret_cast<const bf16x8*>(As + (wm * 64 + i * 16 + col) * 64 + ((ks * 4 + qd) ^ c7) * 8);
#pragma unroll
      for (int i = 0; i < 4; i++)
        bfr[i] = *reinterpret_cast<const bf16x8*>(Bs + (wn * 64 + i * 16 + col) * 64 + ((ks * 4 + qd) ^ c7) * 8);
#pragma unroll
      for (int i = 0; i < 4; i++)
#pragma unroll
        for (int j = 0; j < 4; j++)
          acc[i][j] = MFMA16(af[i], bfr[j], acc[i][j]);
    }
  }

#pragma unroll
  for (int i = 0; i < 4; i++) {
#pragma unroll
    for (int j = 0; j < 4; j++) {
      const int mb = m0 + wm * 64 + i * 16 + qd * 4;
      const int n = n0 + wn * 64 + j * 16 + col;
      if (MODE == 0) {
        const int seg = n >> 10;
        const int h = (n & 1023) >> 6, dd = n & 63;
#pragma unroll
        for (int r = 0; r < 4; r++) {
          const int m = mb + r;
          const int bb = m >> 11, l = m & 2047;
          const float v = acc[i][j][r];
          if (seg == 0)
            QB[((size_t)(bb * 16 + h) * 2048 + l) * 64 + dd] = (bf16)(v * 0.125f);
          else if (seg == 1)
            KB[((size_t)(bb * 16 + h) * 2048 + l) * 64 + dd] = (bf16)v;
          else
            VTB[((size_t)(bb * 16 + h) * 64 + dd) * 2048 + l] = (bf16)v;
        }
      } else {
#pragma unroll
        for (int r = 0; r < 4; r++) {
          const int m = mb + r;
          Y[(size_t)m * 1024 + n] = acc[i][j][r] + X[(size_t)m * 1024 + n];
        }
      }
    }
  }
}

// ---------------- flash attention: S^T trick + dbuf + pipeline + swizzle ----------------
__global__ __launch_bounds__(256) void k_attn(const bf16* __restrict__ QB, const bf16* __restrict__ KB,
                                              const bf16* __restrict__ VTB, bf16* __restrict__ OB) {
  __shared__ __align__(16) bf16 Ks[2][64 * 64];  // [buf][perm(kpos)][dk], chunk-swizzled
  __shared__ __align__(16) bf16 Vs[2][64 * 64];  // [buf][dv][kpos], chunk-swizzled
  const int t = threadIdx.x;
  const int lane = t & 63, wv = t >> 6;
  const int qd = lane >> 4, col = lane & 15;
  const int c7 = col & 7;
  const int bh = blockIdx.y;
  const int qr = blockIdx.x * 128 + wv * 32;
  const int lrow0 = wv * 8 + (lane >> 3);
  const int scol = ((lane & 7) ^ (lane >> 3)) * 8;  // swizzled source chunk
  // K inverse permutation: LDS row -> kpos (perm: kpos[b4b3|b2|b1b0] -> lds[b2|b4b3|b1b0])
  const int kg0 = ((lrow0 >> 5) << 5) + (((lrow0 >> 2) & 3) << 3) + (((lrow0 >> 4) & 1) << 2) + (lrow0 & 3);
  const int r1 = lrow0 + 32;
  const int kg1 = ((r1 >> 5) << 5) + (((r1 >> 2) & 3) << 3) + (((r1 >> 4) & 1) << 2) + (r1 & 3);
  const bf16* Kg0 = KB + ((size_t)bh * 2048 + kg0) * 64 + scol;
  const bf16* Kg1 = KB + ((size_t)bh * 2048 + kg1) * 64 + scol;
  const bf16* Vg0 = VTB + ((size_t)bh * 64 + lrow0) * 2048 + scol;
  const bf16* Vg1 = VTB + ((size_t)bh * 64 + lrow0 + 32) * 2048 + scol;

  bf16x8 bQ[2][2];
#pragma unroll
  for (int qt = 0; qt < 2; qt++)
#pragma unroll
    for (int s = 0; s < 2; s++)
      bQ[qt][s] = *reinterpret_cast<const bf16x8*>(QB + ((size_t)bh * 2048 + qr + qt * 16 + col) * 64 + s * 32 + qd * 8);

  floatx4 oacc[2][4] = {};
  float lsum[2] = {0.f, 0.f};
  floatx4 scur[2][4];
  int pk[2][4][2];

#define STAGE(i)                                                      \
  do {                                                                \
    const int b_ = (i) & 1;                                           \
    gll16(Kg0 + (size_t)(i) * 4096, &Ks[b_][(wv * 8) * 64]);          \
    gll16(Kg1 + (size_t)(i) * 4096, &Ks[b_][(32 + wv * 8) * 64]);     \
    gll16(Vg0 + (i) * 64, &Vs[b_][(wv * 8) * 64]);                    \
    gll16(Vg1 + (i) * 64, &Vs[b_][(32 + wv * 8) * 64]);               \
  } while (0)

#define QK(i)                                                                                       \
  do {                                                                                              \
    const bf16* ks_ = Ks[(i) & 1];                                                                  \
    _Pragma("unroll") for (int nt = 0; nt < 4; nt++) {                                              \
      bf16x8 a0 = *reinterpret_cast<const bf16x8*>(ks_ + (nt * 16 + col) * 64 + (qd ^ c7) * 8);     \
      bf16x8 a1 = *reinterpret_cast<const bf16x8*>(ks_ + (nt * 16 + col) * 64 + ((4 + qd) ^ c7) * 8); \
      _Pragma("unroll") for (int qt = 0; qt < 2; qt++) {                                            \
        floatx4 z = {0.f, 0.f, 0.f, 0.f};                                                           \
        z = MFMA16(a0, bQ[qt][0], z);                                                               \
        z = MFMA16(a1, bQ[qt][1], z);                                                               \
        scur[qt][nt] = z;                                                                           \
      }                                                                                             \
    }                                                                                               \
  } while (0)

#define EXPPACK()                                                                               \
  do {                                                                                          \
    _Pragma("unroll") for (int qt = 0; qt < 2; qt++) {                                          \
      _Pragma("unroll") for (int nt = 0; nt < 4; nt++) {                                        \
        const float e0 = __expf(scur[qt][nt][0]), e1 = __expf(scur[qt][nt][1]);                 \
        const float e2 = __expf(scur[qt][nt][2]), e3 = __expf(scur[qt][nt][3]);                 \
        lsum[qt] += (e0 + e1) + (e2 + e3);                                                      \
        bf16x2 p01, p23;                                                                        \
        p01[0] = (bf16)e0; p01[1] = (bf16)e1;                                                   \
        p23[0] = (bf16)e2; p23[1] = (bf16)e3;                                                   \
        pk[qt][nt][0] = __builtin_bit_cast(int, p01);                                           \
        pk[qt][nt][1] = __builtin_bit_cast(int, p23);                                           \
      }                                                                                         \
    }                                                                                           \
  } while (0)

#define PV(i)                                                                                       \
  do {                                                                                              \
    const bf16* vs_ = Vs[(i) & 1];                                                                  \
    bf16x8 bV[4][2];                                                                                \
    _Pragma("unroll") for (int nd = 0; nd < 4; nd++) {                                              \
      bV[nd][0] = *reinterpret_cast<const bf16x8*>(vs_ + (nd * 16 + col) * 64 + (qd ^ c7) * 8);     \
      bV[nd][1] = *reinterpret_cast<const bf16x8*>(vs_ + (nd * 16 + col) * 64 + ((4 + qd) ^ c7) * 8); \
    }                                                                                               \
    _Pragma("unroll") for (int qt = 0; qt < 2; qt++) {                                              \
      _Pragma("unroll") for (int s = 0; s < 2; s++) {                                               \
        intx4 w;                                                                                    \
        w[0] = pk[qt][2 * s][0]; w[1] = pk[qt][2 * s][1];                                           \
        w[2] = pk[qt][2 * s + 1][0]; w[3] = pk[qt][2 * s + 1][1];                                   \
        const bf16x8 aP = __builtin_bit_cast(bf16x8, w);                                            \
        _Pragma("unroll") for (int nd = 0; nd < 4; nd++)                                            \
          oacc[qt][nd] = MFMA16(aP, bV[nd][s], oacc[qt][nd]);                                       \
      }                                                                                             \
    }                                                                                               \
  } while (0)

  STAGE(0);
  __syncthreads();
  QK(0);
  for (int i = 1; i < 32; i++) {
    __syncthreads();  // A: tile i-2 reads complete on all waves
    STAGE(i);
    EXPPACK();
    PV(i - 1);
    __syncthreads();  // B: tile i staged
    QK(i);
  }
  EXPPACK();
  PV(31);

#pragma unroll
  for (int qt = 0; qt < 2; qt++) {
    lsum[qt] += __shfl_xor(lsum[qt], 16);
    lsum[qt] += __shfl_xor(lsum[qt], 32);
  }
  const int bb = bh >> 4, h = bh & 15;
#pragma unroll
  for (int qt = 0; qt < 2; qt++) {
#pragma unroll
    for (int r = 0; r < 4; r++) {
      const float linv = 1.f / __shfl(lsum[qt], qd * 4 + r);
      const size_t m = (size_t)bb * 2048 + qr + qt * 16 + qd * 4 + r;
#pragma unroll
      for (int nd = 0; nd < 4; nd++)
        OB[m * 1024 + h * 64 + nd * 16 + col] = (bf16)(oacc[qt][nd][r] * linv);
    }
  }
#undef STAGE
#undef QK
#undef EXPPACK
#undef PV
}

// ---------------- LayerNorm ----------------
__global__ __launch_bounds__(256) void k_ln(const float* __restrict__ Yin, const float* __restrict__ gamma,
                                            const float* __restrict__ beta, float* __restrict__ out) {
  __shared__ float red[8];
  const int row = blockIdx.x, t = threadIdx.x;
  const float4 v = *reinterpret_cast<const float4*>(Yin + (size_t)row * 1024 + t * 4);
  float s = v.x + v.y + v.z + v.w;
  float ss = v.x * v.x + v.y * v.y + v.z * v.z + v.w * v.w;
#pragma unroll
  for (int d = 1; d < 64; d <<= 1) {
    s += __shfl_xor(s, d);
    ss += __shfl_xor(ss, d);
  }
  if ((t & 63) == 0) {
    red[t >> 6] = s;
    red[4 + (t >> 6)] = ss;
  }
  __syncthreads();
  s = red[0] + red[1] + red[2] + red[3];
  ss = red[4] + red[5] + red[6] + red[7];
  const float mu = s * (1.f / 1024.f);
  const float var = ss * (1.f / 1024.f) - mu * mu;
  const float rs = rsqrtf(var + 1e-6f);
  const float4 g = *reinterpret_cast<const float4*>(gamma + t * 4);
  const float4 bt = *reinterpret_cast<const float4*>(beta + t * 4);
  float4 o;
  o.x = (v.x - mu) * rs * g.x + bt.x;
  o.y = (v.y - mu) * rs * g.y + bt.y;
  o.z = (v.z - mu) * rs * g.z + bt.z;
  o.w = (v.w - mu) * rs * g.w + bt.w;
  *reinterpret_cast<float4*>(out + (size_t)row * 1024 + t * 4) = o;
}

extern "C" void kernel_launch(void* const* d_in, const int* in_sizes, int n_in,
                              void* d_out, int out_size, void* d_ws, size_t ws_size,
                              hipStream_t stream) {
  (void)in_sizes; (void)n_in; (void)out_size; (void)ws_size;
  const float* x = (const float*)d_in[0];
  const float* Wq = (const float*)d_in[1];
  const float* Wk = (const float*)d_in[2];
  const float* Wv = (const float*)d_in[3];
  const float* Wo = (const float*)d_in[4];
  const float* gamma = (const float*)d_in[5];
  const float* beta = (const float*)d_in[6];

  char* ws = (char*)d_ws;
  const size_t MB = 1ull << 20;
  bf16* XB = (bf16*)(ws);
  bf16* OB = (bf16*)(ws);
  bf16* WT = (bf16*)(ws + 8 * MB);
  bf16* QB = (bf16*)(ws + 16 * MB);
  bf16* KB = (bf16*)(ws + 24 * MB);
  bf16* VTB = (bf16*)(ws + 32 * MB);
  float* Y = (float*)(ws + 16 * MB);

  k_prep_x<<<4096, 256, 0, stream>>>(x, XB);
  k_prep_w<<<dim3(32, 32, 4), dim3(32, 8), 0, stream>>>(Wq, Wk, Wv, Wo, WT);
  k_gemm<0><<<dim3(32, 24), 256, 0, stream>>>(XB, WT, nullptr, nullptr, QB, KB, VTB);
  k_attn<<<dim3(16, 32), 256, 0, stream>>>(QB, KB, VTB, OB);
  k_gemm<1><<<dim3(32, 8), 256, 0, stream>>>(OB, WT + (size_t)3072 * 1024, x, Y,
                                             nullptr, nullptr, nullptr);
  k_ln<<<4096, 256, 0, stream>>>(Y, gamma, beta, (float*)d_out);
}